// Round 3
// baseline (325.897 us; speedup 1.0000x reference)
//
#include <hip/hip_runtime.h>
#include <hip/hip_bf16.h>

#define NN 50000
#define EE 800000

__device__ __forceinline__ float bflo(unsigned u) { return __uint_as_float(u << 16); }
__device__ __forceinline__ float bfhi(unsigned u) { return __uint_as_float(u & 0xffff0000u); }

// Writes flag=1 if float tensors are bf16, 0 if f32.
// bf16 data: low halfword of each 32b word is a bf16 of ~N(0,1) -> exponent
// field in [100,140] essentially always. f32 data: those bits are low
// mantissa bits, ~uniform -> ~16% hit rate. Threshold 32/64.
__global__ void detect_dtype(const unsigned* __restrict__ xw, int* __restrict__ flag) {
    if (threadIdx.x == 0 && blockIdx.x == 0) {
        int cnt = 0;
        for (int i = 0; i < 64; i++) {
            unsigned e = (xw[i] >> 7) & 0xFFu;
            if (e >= 100u && e <= 140u) cnt++;
        }
        *flag = (cnt >= 32) ? 1 : 0;
    }
}

template <bool BF16>
__device__ __forceinline__ void edge_body(
    const void* __restrict__ xv, const int* __restrict__ ei,
    const void* __restrict__ eav, const void* __restrict__ Wev,
    const void* __restrict__ bev, float* __restrict__ agg)
{
    const int tid = threadIdx.x;
    const int d   = tid & 63;
    const int sub = tid >> 6;

    // index dtype auto-detect (kept as belt-and-braces; proven int32 so far)
    const int oddor = ei[1] | ei[3] | ei[5] | ei[7] | ei[9] | ei[11] | ei[13] | ei[15];
    const bool idx64 = (oddor == 0);
    const long long* __restrict__ ei64 = (const long long*)ei;

    float we[16];
    float bed;
    if constexpr (BF16) {
        const __hip_bfloat16* We = (const __hip_bfloat16*)Wev;
        const __hip_bfloat16* be = (const __hip_bfloat16*)bev;
#pragma unroll
        for (int k = 0; k < 16; k++) we[k] = __bfloat162float(We[k * 64 + d]);
        bed = __bfloat162float(be[d]);
    } else {
        const float* We = (const float*)Wev;
        const float* be = (const float*)bev;
#pragma unroll
        for (int k = 0; k < 16; k++) we[k] = We[k * 64 + d];
        bed = be[d];
    }

    const int stride = gridDim.x * 4;
    for (int e = blockIdx.x * 4 + sub; e < EE; e += stride) {
        int src, dst;
        if (idx64) { src = (int)ei64[e]; dst = (int)ei64[EE + e]; }
        else       { src = ei[e];        dst = ei[EE + e]; }

        float a[16];
        if constexpr (BF16) {
            const uint4* row = (const uint4*)((const __hip_bfloat16*)eav + (size_t)e * 16);
            const uint4 p0 = row[0];
            const uint4 p1 = row[1];
            a[0]=bflo(p0.x); a[1]=bfhi(p0.x); a[2]=bflo(p0.y); a[3]=bfhi(p0.y);
            a[4]=bflo(p0.z); a[5]=bfhi(p0.z); a[6]=bflo(p0.w); a[7]=bfhi(p0.w);
            a[8]=bflo(p1.x); a[9]=bfhi(p1.x); a[10]=bflo(p1.y); a[11]=bfhi(p1.y);
            a[12]=bflo(p1.z); a[13]=bfhi(p1.z); a[14]=bflo(p1.w); a[15]=bfhi(p1.w);
        } else {
            const float4* row = (const float4*)((const float*)eav + (size_t)e * 16);
            const float4 q0 = row[0], q1 = row[1], q2 = row[2], q3 = row[3];
            a[0]=q0.x; a[1]=q0.y; a[2]=q0.z; a[3]=q0.w;
            a[4]=q1.x; a[5]=q1.y; a[6]=q1.z; a[7]=q1.w;
            a[8]=q2.x; a[9]=q2.y; a[10]=q2.z; a[11]=q2.w;
            a[12]=q3.x; a[13]=q3.y; a[14]=q3.z; a[15]=q3.w;
        }

        float acc = bed;
#pragma unroll
        for (int k = 0; k < 16; k++) acc = fmaf(a[k], we[k], acc);

        float xs;
        if constexpr (BF16) xs = __bfloat162float(((const __hip_bfloat16*)xv)[(size_t)src * 64 + d]);
        else                xs = ((const float*)xv)[(size_t)src * 64 + d];

        float msg = fmaxf(acc + xs, 0.0f);
        atomicAdd(&agg[(size_t)dst * 64 + d], msg);
    }
}

__global__ __launch_bounds__(256) void edge_agg_kernel(
    const void* x, const int* ei, const void* ea,
    const void* We, const void* be, float* agg, const int* flag)
{
    if (*flag) edge_body<true>(x, ei, ea, We, be, agg);
    else       edge_body<false>(x, ei, ea, We, be, agg);
}

template <bool BF16>
__device__ __forceinline__ void mlp_body(
    const void* __restrict__ xv, const float* __restrict__ agg,
    const void* __restrict__ W1v, const void* __restrict__ b1v,
    const void* __restrict__ W2v, const void* __restrict__ b2v,
    void* __restrict__ outv)
{
    __shared__ float sh[4][64];
    __shared__ float st[4][64];
    const int tid = threadIdx.x;
    const int d   = tid & 63;
    const int w   = tid >> 6;

    float w1c[64], w2c[64], b1d, b2d;
    if constexpr (BF16) {
        const __hip_bfloat16* W1 = (const __hip_bfloat16*)W1v;
        const __hip_bfloat16* W2 = (const __hip_bfloat16*)W2v;
#pragma unroll
        for (int k = 0; k < 64; k++) {
            w1c[k] = __bfloat162float(W1[k * 64 + d]);
            w2c[k] = __bfloat162float(W2[k * 64 + d]);
        }
        b1d = __bfloat162float(((const __hip_bfloat16*)b1v)[d]);
        b2d = __bfloat162float(((const __hip_bfloat16*)b2v)[d]);
    } else {
        const float* W1 = (const float*)W1v;
        const float* W2 = (const float*)W2v;
#pragma unroll
        for (int k = 0; k < 64; k++) {
            w1c[k] = W1[k * 64 + d];
            w2c[k] = W2[k * 64 + d];
        }
        b1d = ((const float*)b1v)[d];
        b2d = ((const float*)b2v)[d];
    }

    const int stride = gridDim.x * 4;
    const int iters  = (NN + stride - 1) / stride;
    int node = blockIdx.x * 4 + w;
    for (int it = 0; it < iters; it++, node += stride) {
        const bool valid = node < NN;
        if (valid) {
            float xs;
            if constexpr (BF16) xs = __bfloat162float(((const __hip_bfloat16*)xv)[(size_t)node * 64 + d]);
            else                xs = ((const float*)xv)[(size_t)node * 64 + d];
            sh[w][d] = xs + agg[(size_t)node * 64 + d];
        }
        __syncthreads();

        float t = b1d;
        const float4* hv = (const float4*)sh[w];
#pragma unroll
        for (int k = 0; k < 16; k++) {
            const float4 hq = hv[k];
            t = fmaf(hq.x, w1c[4 * k],     t);
            t = fmaf(hq.y, w1c[4 * k + 1], t);
            t = fmaf(hq.z, w1c[4 * k + 2], t);
            t = fmaf(hq.w, w1c[4 * k + 3], t);
        }
        t = fmaxf(t, 0.0f);
        st[w][d] = t;
        __syncthreads();

        float o = b2d;
        const float4* tv = (const float4*)st[w];
#pragma unroll
        for (int k = 0; k < 16; k++) {
            const float4 tq = tv[k];
            o = fmaf(tq.x, w2c[4 * k],     o);
            o = fmaf(tq.y, w2c[4 * k + 1], o);
            o = fmaf(tq.z, w2c[4 * k + 2], o);
            o = fmaf(tq.w, w2c[4 * k + 3], o);
        }
        if (valid) {
            if constexpr (BF16) ((__hip_bfloat16*)outv)[(size_t)node * 64 + d] = __float2bfloat16(o);
            else                ((float*)outv)[(size_t)node * 64 + d] = o;
        }
    }
}

__global__ __launch_bounds__(256) void mlp_kernel(
    const void* x, const float* agg,
    const void* W1, const void* b1, const void* W2, const void* b2,
    void* out, const int* flag)
{
    if (*flag) mlp_body<true>(x, agg, W1, b1, W2, b2, out);
    else       mlp_body<false>(x, agg, W1, b1, W2, b2, out);
}

extern "C" void kernel_launch(void* const* d_in, const int* in_sizes, int n_in,
                              void* d_out, int out_size, void* d_ws, size_t ws_size,
                              hipStream_t stream) {
    const void* x          = d_in[0];
    const int*  edge_index = (const int*)d_in[1];
    const void* edge_attr  = d_in[2];
    const void* We         = d_in[3];
    const void* be         = d_in[4];
    const void* W1         = d_in[5];
    const void* b1         = d_in[6];
    const void* W2         = d_in[7];
    const void* b2         = d_in[8];

    float* agg = (float*)d_ws;                                   // NN*64 f32 = 12.8 MB
    int*   flag = (int*)((char*)d_ws + (size_t)NN * 64 * sizeof(float));

    hipMemsetAsync(agg, 0, (size_t)NN * 64 * sizeof(float), stream);
    hipLaunchKernelGGL(detect_dtype, dim3(1), dim3(64), 0, stream,
                       (const unsigned*)x, flag);
    hipLaunchKernelGGL(edge_agg_kernel, dim3(4096), dim3(256), 0, stream,
                       x, edge_index, edge_attr, We, be, agg, flag);
    hipLaunchKernelGGL(mlp_kernel, dim3(2048), dim3(256), 0, stream,
                       x, agg, W1, b1, W2, b2, d_out, flag);
}